// Round 4
// baseline (79.244 us; speedup 1.0000x reference)
//
#include <hip/hip_runtime.h>

// Problem: x [64,1,257,257] f32, conv_w [1,1,2,2], conv_b [1], qparams [2,4].
// Output [64,2,256,256] f32 = concat(conv-relu, qmap) on channel axis.
//
// Analytic collapse (re-derived independently R2; verified on-harness in the
// prior session, absmax 0.0625):
//   - qparams provably irrelevant: circuit tail is P*D2*P*D1 (unit-modulus
//     diagonals + basis permutations) — Z-basis probabilities unchanged.
//   - expval = cos(TL)*cos(TR)*cos(BR): bit0 of F^2(k) = b0^b1^b3 for the
//     'full' CNOT chain applied twice; product state factorizes the sum.
//
// R3 design: LDS staging.
//   R2 had 15 scalar global loads/thread at 16B lane stride -> each wave-load
//   spans ~17 cache lines for ~4 lines of fresh data (~5x L1 request
//   amplification); INW=257 misaligns rows so float4 global loads are
//   impossible. Fix: stage 9x257 rows per block into LDS with fully coalesced
//   dword loads; compute from LDS via aligned, conflict-free ds_read_b128.
// R3b: + non-temporal output stores (write-once data; keep L2 for the input's
//   1-row inter-block overlap), + hoist uniform weight loads ahead of staging.
// R5 (this round): fix compile error — __builtin_nontemporal_store requires a
//   native clang vector, not HIP's struct float4. Use ext_vector_type(4).
//   No other changes; this is still the R3b design's first measurement.

#define BATCH 64
#define INH   257
#define INW   257
#define OH    256
#define OW    256
#define RG    32            // row-groups per image: 8 output rows each
#define LROWS 9             // input rows staged per block
#define LPITCH 264          // LDS row pitch in floats (multiple of 4, padded)

typedef float fvec4 __attribute__((ext_vector_type(4)));

__device__ __forceinline__ void store_nt4(float* p, float x, float y, float z, float w)
{
    fvec4 v; v.x = x; v.y = y; v.z = z; v.w = w;
    __builtin_nontemporal_store(v, (fvec4*)p);
}

__global__ __launch_bounds__(256) void conv_enh_lds(
    const float* __restrict__ x,
    const float* __restrict__ cw,
    const float* __restrict__ cb,
    float* __restrict__ out)
{
    __shared__ float lds[LROWS * LPITCH];   // 9*264*4 = 9504 B

    const int tid = threadIdx.x;
    const int blk = blockIdx.x;
    const int rg  = blk & (RG - 1);          // 0..31 -> input rows 8*rg .. 8*rg+8
    const int b   = blk >> 5;                // 0..63

    // uniform weight/bias loads issued first: latency hides under staging
    const float w00 = cw[0], w01 = cw[1], w10 = cw[2], w11 = cw[3];
    const float bias = cb[0];

    const int r_base = rg * 8;
    const float* __restrict__ src =
        x + (size_t)b * INH * INW + (size_t)r_base * INW;

    // ---- stage: 9 rows x 257 cols = 2313 floats, coalesced dword loads ----
    #pragma unroll
    for (int k = 0; k < 10; ++k) {
        const int idx = tid + k * 256;
        if (idx < LROWS * INW) {
            const int r = idx / INW;         // const-div -> mul_hi, cheap
            const int c = idx - r * INW;
            lds[r * LPITCH + c] = src[idx];
        }
    }
    __syncthreads();

    // one wave = one output row-pair across the full width
    const int j  = tid & 63;                 // 0..63 -> output cols 4j..4j+3
    const int il = tid >> 6;                 // 0..3  -> local row-pair
    const int c0 = 4 * j;

    const float* __restrict__ l0 = &lds[(2 * il) * LPITCH + c0]; // 16B-aligned
    const float* __restrict__ l1 = l0 + LPITCH;
    const float* __restrict__ l2 = l1 + LPITCH;

    const fvec4 A = *(const fvec4*)l0;  const float a4 = l0[4];
    const fvec4 M = *(const fvec4*)l1;  const float m4 = l1[4];
    const fvec4 Z = *(const fvec4*)l2;  const float z4 = l2[4];

    // cross-correlation + bias + ReLU; top row (r0) and bottom row (r0+1)
    const float t0 = fmaxf(fmaf(w11, M.y, fmaf(w10, M.x, fmaf(w01, A.y, fmaf(w00, A.x, bias)))), 0.f);
    const float t1 = fmaxf(fmaf(w11, M.z, fmaf(w10, M.y, fmaf(w01, A.z, fmaf(w00, A.y, bias)))), 0.f);
    const float t2 = fmaxf(fmaf(w11, M.w, fmaf(w10, M.z, fmaf(w01, A.w, fmaf(w00, A.z, bias)))), 0.f);
    const float t3 = fmaxf(fmaf(w11, m4,  fmaf(w10, M.w, fmaf(w01, a4,  fmaf(w00, A.w, bias)))), 0.f);
    const float u0 = fmaxf(fmaf(w11, Z.y, fmaf(w10, Z.x, fmaf(w01, M.y, fmaf(w00, M.x, bias)))), 0.f);
    const float u1 = fmaxf(fmaf(w11, Z.z, fmaf(w10, Z.y, fmaf(w01, M.z, fmaf(w00, M.y, bias)))), 0.f);
    const float u2 = fmaxf(fmaf(w11, Z.w, fmaf(w10, Z.z, fmaf(w01, M.w, fmaf(w00, M.z, bias)))), 0.f);
    const float u3 = fmaxf(fmaf(w11, z4,  fmaf(w10, Z.w, fmaf(w01, m4,  fmaf(w00, M.w, bias)))), 0.f);

    // qmap per 2x2 patch: cos(TL)*cos(TR)*cos(BR)
    const float q0 = __cosf(t0) * __cosf(t1) * __cosf(u1);
    const float q1 = __cosf(t2) * __cosf(t3) * __cosf(u3);

    const int r0 = r_base + 2 * il;
    float* __restrict__ o0 = out + (size_t)b * 2 * OH * OW + (size_t)r0 * OW + c0;
    float* __restrict__ o1 = o0 + OH * OW;

    // out is write-once: non-temporal stores keep L2 for the input overlap
    store_nt4(o0,      t0, t1, t2, t3);
    store_nt4(o0 + OW, u0, u1, u2, u3);
    store_nt4(o1,      q0, q0, q1, q1);
    store_nt4(o1 + OW, q0, q0, q1, q1);
}

extern "C" void kernel_launch(void* const* d_in, const int* in_sizes, int n_in,
                              void* d_out, int out_size, void* d_ws, size_t ws_size,
                              hipStream_t stream)
{
    const float* x  = (const float*)d_in[0];
    const float* cw = (const float*)d_in[1];
    const float* cb = (const float*)d_in[2];
    // d_in[3] (qparams) provably does not affect the output.
    float* out = (float*)d_out;

    const int grid  = BATCH * RG;   // 2048 blocks
    const int block = 256;
    conv_enh_lds<<<grid, block, 0, stream>>>(x, cw, cb, out);
}